// Round 1
// baseline (34.419 us; speedup 1.0000x reference)
//
#include <hip/hip_runtime.h>
#include <hip/hip_bf16.h>
#include <cstdint>

// VQ-VAE vector quantize: N=65536 vectors, D=64, K=512 codes.
// d_in[0]: inputs fp32 [65536*64], d_in[1]: embeddings fp32 [512*64]
// d_out:   [0] = loss, [1..4194304] = latent (= gathered embeddings)

typedef __attribute__((ext_vector_type(8))) short bf16x8;
typedef __attribute__((ext_vector_type(4))) float f32x4;

__device__ __forceinline__ short f2bf(float f) {
    uint32_t u = __builtin_bit_cast(uint32_t, f);
    u += 0x7FFFu + ((u >> 16) & 1u);   // round-to-nearest-even
    return (short)(u >> 16);
}

// ---------------- Kernel 1: bf16 MFMA distances + packed argmin ----------------
// Grid: 256 blocks x 256 threads. Block handles 256 rows (4 waves x 64 rows).
// LDS: B fragments pre-arranged in MFMA fragment order -> linear conflict-free
// ds_read_b128, plus ee[512] = ||e_k||^2.
__launch_bounds__(256, 2)
__global__ void vq_argmin(const float* __restrict__ flat,
                          const float* __restrict__ emb,
                          int* __restrict__ idx_out) {
    __shared__ bf16x8 bfrag[4096];   // [ct(32)][ks(2)][lane(64)] = 64 KB
    __shared__ float  ee[512];       // 2 KB

    const int tid = threadIdx.x;

    // stage ||e_k||^2
    for (int c = tid; c < 512; c += 256) {
        float s = 0.f;
        #pragma unroll 8
        for (int d = 0; d < 64; ++d) { float v = emb[c * 64 + d]; s = fmaf(v, v, s); }
        ee[c] = s;
    }
    // stage B fragments: lane ln of tile ct holds code (ct*16 + ln&15),
    // dims ks*32 + (ln>>4)*8 .. +7  (exact mfma_f32_16x16x32_bf16 B layout)
    for (int s = tid; s < 4096; s += 256) {
        const int ct = s >> 7, ks = (s >> 6) & 1, ln = s & 63;
        const int code = (ct << 4) | (ln & 15);
        const int d0 = ks * 32 + ((ln >> 4) << 3);
        const float* src = emb + code * 64 + d0;
        float4 v0 = *(const float4*)src;
        float4 v1 = *(const float4*)(src + 4);
        bf16x8 b;
        b[0] = f2bf(v0.x); b[1] = f2bf(v0.y); b[2] = f2bf(v0.z); b[3] = f2bf(v0.w);
        b[4] = f2bf(v1.x); b[5] = f2bf(v1.y); b[6] = f2bf(v1.z); b[7] = f2bf(v1.w);
        bfrag[s] = b;
    }
    __syncthreads();

    const int lane = tid & 63, wid = tid >> 6;
    const int rb = blockIdx.x * 256 + wid * 64;

    // A fragments: 4 row-tiles x 2 k-steps, lane holds row rb+mt*16+(lane&15),
    // dims ks*32+(lane>>4)*8 .. +7
    bf16x8 a[4][2];
    #pragma unroll
    for (int mt = 0; mt < 4; ++mt) {
        #pragma unroll
        for (int ks = 0; ks < 2; ++ks) {
            const int row = rb + mt * 16 + (lane & 15);
            const float* src = flat + row * 64 + ks * 32 + ((lane >> 4) << 3);
            float4 v0 = *(const float4*)src;
            float4 v1 = *(const float4*)(src + 4);
            bf16x8 f;
            f[0] = f2bf(v0.x); f[1] = f2bf(v0.y); f[2] = f2bf(v0.z); f[3] = f2bf(v0.w);
            f[4] = f2bf(v1.x); f[5] = f2bf(v1.y); f[6] = f2bf(v1.z); f[7] = f2bf(v1.w);
            a[mt][ks] = f;
        }
    }

    // running packed min: value bits 31..9, code index in bits 8..0
    float pm[16];
    #pragma unroll
    for (int i = 0; i < 16; ++i) pm[i] = __builtin_bit_cast(float, 0x7F800000u);

    const int cb = lane & 15;
    for (int ct = 0; ct < 32; ++ct) {
        bf16x8 b0 = bfrag[ct * 128 + lane];
        bf16x8 b1 = bfrag[ct * 128 + 64 + lane];
        const int colv = (ct << 4) | cb;
        const float eec = ee[colv];
        #pragma unroll
        for (int mt = 0; mt < 4; ++mt) {
            f32x4 acc = {0.f, 0.f, 0.f, 0.f};
            acc = __builtin_amdgcn_mfma_f32_16x16x32_bf16(a[mt][0], b0, acc, 0, 0, 0);
            acc = __builtin_amdgcn_mfma_f32_16x16x32_bf16(a[mt][1], b1, acc, 0, 0, 0);
            #pragma unroll
            for (int j = 0; j < 4; ++j) {
                // dist' = ||e||^2 - 2 x.e  (row-constant ||x||^2 dropped)
                float d = fmaf(-2.f, acc[j], eec);
                uint32_t dp = (__builtin_bit_cast(uint32_t, d) & 0xFFFFFE00u) | (uint32_t)colv;
                float fd = __builtin_bit_cast(float, dp);
                pm[mt * 4 + j] = fminf(pm[mt * 4 + j], fd);
            }
        }
    }

    // butterfly min over the 16 lanes (column classes) within each lane group
    #pragma unroll
    for (int m = 1; m < 16; m <<= 1) {
        #pragma unroll
        for (int i = 0; i < 16; ++i)
            pm[i] = fminf(pm[i], __shfl_xor(pm[i], m, 64));
    }

    if ((lane & 15) == 0) {
        const int g = lane >> 4;  // row sub-group
        #pragma unroll
        for (int mt = 0; mt < 4; ++mt) {
            #pragma unroll
            for (int j = 0; j < 4; ++j) {
                const int row = rb + mt * 16 + g * 4 + j;
                idx_out[row] = (int)(__builtin_bit_cast(uint32_t, pm[mt * 4 + j]) & 0x1FFu);
            }
        }
    }
}

// ---------------- Kernel 2: gather + latent write + squared-error partials ----------------
__launch_bounds__(256)
__global__ void vq_gather(const float* __restrict__ flat,
                          const float* __restrict__ emb,
                          const int* __restrict__ idx,
                          float* __restrict__ out,
                          float* __restrict__ partials) {
    __shared__ float red[4];
    const int tid = threadIdx.x;
    const float4* __restrict__ emb4 = (const float4*)emb;
    const float4* __restrict__ flat4 = (const float4*)flat;

    float acc = 0.f;
    long g0 = (long)blockIdx.x * 256 + tid;
    for (long g4 = g0; g4 < 1048576; g4 += 524288) {   // 4194304/4 float4s
        const int n = (int)(g4 >> 4), q = (int)(g4 & 15);
        const int i = idx[n];
        float4 e = emb4[i * 16 + q];
        float4 x = flat4[g4];
        float* o = out + 1 + 4 * g4;   // +1 float offset: scalar stores (4B-aligned only)
        o[0] = e.x; o[1] = e.y; o[2] = e.z; o[3] = e.w;
        float dx = e.x - x.x, dy = e.y - x.y, dz = e.z - x.z, dw = e.w - x.w;
        acc += dx * dx + dy * dy + dz * dz + dw * dw;
    }
    #pragma unroll
    for (int m = 32; m; m >>= 1) acc += __shfl_down(acc, m, 64);
    if ((tid & 63) == 0) red[tid >> 6] = acc;
    __syncthreads();
    if (tid == 0) partials[blockIdx.x] = red[0] + red[1] + red[2] + red[3];
}

// ---------------- Kernel 3: deterministic final reduce ----------------
__launch_bounds__(256)
__global__ void vq_loss(const float* __restrict__ partials, float* __restrict__ out) {
    __shared__ float red[4];
    const int tid = threadIdx.x;
    float acc = 0.f;
    for (int i = tid; i < 2048; i += 256) acc += partials[i];
    #pragma unroll
    for (int m = 32; m; m >>= 1) acc += __shfl_down(acc, m, 64);
    if ((tid & 63) == 0) red[tid >> 6] = acc;
    __syncthreads();
    // loss = 0.25*e_loss + q_loss, both equal mean((e-x)^2) in forward -> 1.25*mse
    if (tid == 0) out[0] = 1.25f * (red[0] + red[1] + red[2] + red[3]) / 4194304.0f;
}

extern "C" void kernel_launch(void* const* d_in, const int* in_sizes, int n_in,
                              void* d_out, int out_size, void* d_ws, size_t ws_size,
                              hipStream_t stream) {
    const float* flat = (const float*)d_in[0];   // [65536,64]
    const float* emb  = (const float*)d_in[1];   // [512,64]
    float* out = (float*)d_out;

    int*   idx      = (int*)d_ws;                              // 65536 ints = 256 KB
    float* partials = (float*)((char*)d_ws + 65536 * sizeof(int));  // 2048 floats

    vq_argmin<<<256, 256, 0, stream>>>(flat, emb, idx);
    vq_gather<<<2048, 256, 0, stream>>>(flat, emb, idx, out, partials);
    vq_loss<<<1, 256, 0, stream>>>(partials, out);
}

// Round 2
// 30.983 us; speedup vs baseline: 1.1109x; 1.1109x over previous
//
#include <hip/hip_runtime.h>
#include <hip/hip_bf16.h>
#include <cstdint>

// VQ-VAE vector quantize, fused: N=65536 vectors, D=64, K=512 codes.
// d_in[0]: inputs fp32 [65536*64], d_in[1]: embeddings fp32 [512*64]
// d_out:   [0] = loss, [1..4194304] = latent (= gathered embeddings)

typedef __attribute__((ext_vector_type(8))) short bf16x8;
typedef __attribute__((ext_vector_type(4))) float f32x4;

__device__ __forceinline__ short f2bf(float f) {
    uint32_t u = __builtin_bit_cast(uint32_t, f);
    u += 0x7FFFu + ((u >> 16) & 1u);   // round-to-nearest-even
    return (short)(u >> 16);
}

// ---------------- Kernel 1: fused distances + argmin + gather + loss partials -------
// 256 blocks x 512 threads (8 waves, 2 waves/SIMD). Block owns 256 rows,
// wave owns 32 rows (2 M-tiles of 16). B fragments staged once in LDS in
// exact MFMA fragment order (linear conflict-free ds_read_b128).
__launch_bounds__(512, 2)
__global__ void vq_fused(const float* __restrict__ flat,
                         const float* __restrict__ emb,
                         float* __restrict__ out,
                         float* __restrict__ partials) {
    __shared__ bf16x8 bfrag[4096];   // [ct(32)][ks(2)][lane(64)] = 64 KB
    __shared__ float  ee[512];       // ||e_k||^2
    __shared__ float  red[8];

    const int tid = threadIdx.x;

    // stage ||e_k||^2 : one code per thread, float4 loads
    {
        const float4* e4 = (const float4*)(emb + tid * 64);
        float s = 0.f;
        #pragma unroll
        for (int q = 0; q < 16; ++q) {
            float4 v = e4[q];
            s = fmaf(v.x, v.x, fmaf(v.y, v.y, fmaf(v.z, v.z, fmaf(v.w, v.w, s))));
        }
        ee[tid] = s;
    }
    // stage B fragments: lane ln of tile ct holds code (ct*16 + ln&15),
    // dims ks*32 + (ln>>4)*8 .. +7  (exact mfma_f32_16x16x32_bf16 B layout)
    for (int s = tid; s < 4096; s += 512) {
        const int ct = s >> 7, ks = (s >> 6) & 1, ln = s & 63;
        const int code = (ct << 4) | (ln & 15);
        const int d0 = ks * 32 + ((ln >> 4) << 3);
        const float* src = emb + code * 64 + d0;
        float4 v0 = *(const float4*)src;
        float4 v1 = *(const float4*)(src + 4);
        bf16x8 b;
        b[0] = f2bf(v0.x); b[1] = f2bf(v0.y); b[2] = f2bf(v0.z); b[3] = f2bf(v0.w);
        b[4] = f2bf(v1.x); b[5] = f2bf(v1.y); b[6] = f2bf(v1.z); b[7] = f2bf(v1.w);
        bfrag[s] = b;
    }
    __syncthreads();

    const int lane = tid & 63, wid = tid >> 6;
    const int rb = blockIdx.x * 256 + wid * 32;   // wave's first row

    // A fragments: 2 row-tiles x 2 k-steps
    bf16x8 a[2][2];
    #pragma unroll
    for (int mt = 0; mt < 2; ++mt) {
        #pragma unroll
        for (int ks = 0; ks < 2; ++ks) {
            const int row = rb + mt * 16 + (lane & 15);
            const float* src = flat + row * 64 + ks * 32 + ((lane >> 4) << 3);
            float4 v0 = *(const float4*)src;
            float4 v1 = *(const float4*)(src + 4);
            bf16x8 f;
            f[0] = f2bf(v0.x); f[1] = f2bf(v0.y); f[2] = f2bf(v0.z); f[3] = f2bf(v0.w);
            f[4] = f2bf(v1.x); f[5] = f2bf(v1.y); f[6] = f2bf(v1.z); f[7] = f2bf(v1.w);
            a[mt][ks] = f;
        }
    }

    // running packed min: value bits 31..9, code index in bits 8..0
    float pm[8];
    #pragma unroll
    for (int i = 0; i < 8; ++i) pm[i] = __builtin_bit_cast(float, 0x7F800000u);

    const int cb = lane & 15;
    for (int ct = 0; ct < 32; ++ct) {
        bf16x8 b0 = bfrag[ct * 128 + lane];
        bf16x8 b1 = bfrag[ct * 128 + 64 + lane];
        const int colv = (ct << 4) | cb;
        const float eec = ee[colv];
        #pragma unroll
        for (int mt = 0; mt < 2; ++mt) {
            f32x4 acc = {0.f, 0.f, 0.f, 0.f};
            acc = __builtin_amdgcn_mfma_f32_16x16x32_bf16(a[mt][0], b0, acc, 0, 0, 0);
            acc = __builtin_amdgcn_mfma_f32_16x16x32_bf16(a[mt][1], b1, acc, 0, 0, 0);
            #pragma unroll
            for (int j = 0; j < 4; ++j) {
                // dist' = ||e||^2 - 2 x.e  (row-constant ||x||^2 dropped)
                float d = fmaf(-2.f, acc[j], eec);
                uint32_t dp = (__builtin_bit_cast(uint32_t, d) & 0xFFFFFE00u) | (uint32_t)colv;
                float fd = __builtin_bit_cast(float, dp);
                pm[mt * 4 + j] = fminf(pm[mt * 4 + j], fd);
            }
        }
    }

    // butterfly min over the 16 column-class lanes; afterwards every lane in a
    // 16-lane group holds the group min for its 8 rows
    #pragma unroll
    for (int m = 1; m < 16; m <<= 1) {
        #pragma unroll
        for (int i = 0; i < 8; ++i)
            pm[i] = fminf(pm[i], __shfl_xor(pm[i], m, 64));
    }

    // broadcast winning code index of each of the wave's 32 rows to all lanes
    int idxr[32];
    #pragma unroll
    for (int r = 0; r < 32; ++r) {
        const int mt = r >> 4, g = (r >> 2) & 3, j = r & 3;
        float v = __shfl(pm[mt * 4 + j], g << 4, 64);
        idxr[r] = (int)(__builtin_bit_cast(uint32_t, v) & 0x1FFu);
    }

    // epilogue: gather + coalesced latent store + loss accumulation.
    // wave's 32 rows are contiguous in out (dword stores, 256B/instr/wave).
    // x re-read hits L2 (block's 64 KB of flat is resident).
    float accL = 0.f;
    float* ob = out + 1 + (long)rb * 64;
    #pragma unroll 8
    for (int it = 0; it < 32; ++it) {
        float ev = emb[idxr[it] * 64 + lane];
        float xv = flat[(long)(rb + it) * 64 + lane];
        ob[it * 64 + lane] = ev;
        float df = ev - xv;
        accL = fmaf(df, df, accL);
    }

    #pragma unroll
    for (int m = 32; m; m >>= 1) accL += __shfl_down(accL, m, 64);
    if (lane == 0) red[wid] = accL;
    __syncthreads();
    if (tid == 0) {
        float s = 0.f;
        #pragma unroll
        for (int i = 0; i < 8; ++i) s += red[i];
        partials[blockIdx.x] = s;
    }
}

// ---------------- Kernel 2: deterministic final reduce (1 wave) ----------------
__launch_bounds__(64)
__global__ void vq_loss(const float* __restrict__ partials, float* __restrict__ out) {
    const int tid = threadIdx.x;
    float acc = partials[tid] + partials[tid + 64] + partials[tid + 128] + partials[tid + 192];
    #pragma unroll
    for (int m = 32; m; m >>= 1) acc += __shfl_down(acc, m, 64);
    // loss = 0.25*e_loss + q_loss, both equal mean((e-x)^2) in forward -> 1.25*mse
    if (tid == 0) out[0] = 1.25f * acc / 4194304.0f;
}

extern "C" void kernel_launch(void* const* d_in, const int* in_sizes, int n_in,
                              void* d_out, int out_size, void* d_ws, size_t ws_size,
                              hipStream_t stream) {
    const float* flat = (const float*)d_in[0];   // [65536,64]
    const float* emb  = (const float*)d_in[1];   // [512,64]
    float* out = (float*)d_out;
    float* partials = (float*)d_ws;              // 256 floats

    vq_fused<<<256, 512, 0, stream>>>(flat, emb, out, partials);
    vq_loss<<<1, 64, 0, stream>>>(partials, out);
}